// Round 8
// baseline (344.053 us; speedup 1.0000x reference)
//
#include <hip/hip_runtime.h>
#include <hip/hip_bf16.h>
#include <stdint.h>

#define NN 50000     // nodes
#define NE 640000    // edges
#define NR 8         // relations
#define NB1 ((NN + 1023) / 1024)   // 49 scan blocks

typedef short bf16x8 __attribute__((ext_vector_type(8)));
typedef float f32x4  __attribute__((ext_vector_type(4)));

__device__ __forceinline__ unsigned short f2bf(float f) {
    union { float f; unsigned u; } v; v.f = f;
    unsigned r = v.u + 0x7FFF + ((v.u >> 16) & 1);
    return (unsigned short)(r >> 16);
}
__device__ __forceinline__ float bf2f(unsigned short s) {
    union { unsigned u; float f; } v; v.u = ((unsigned)s) << 16; return v.f;
}

// ---------------- CSR build by dst ----------------
__global__ void hist_kernel(const int* __restrict__ dst, int* __restrict__ counts) {
    int e = blockIdx.x * 256 + threadIdx.x;
    if (e < NE) atomicAdd(&counts[dst[e]], 1);
}

__global__ __launch_bounds__(1024) void blocksum_kernel(const int* __restrict__ counts,
                                                        int* __restrict__ bsum, int n) {
    __shared__ int ws[16];
    int i = blockIdx.x * 1024 + threadIdx.x;
    int v = (i < n) ? counts[i] : 0;
    #pragma unroll
    for (int d = 32; d > 0; d >>= 1) v += __shfl_down(v, d, 64);
    int wid = threadIdx.x >> 6, lane = threadIdx.x & 63;
    if (lane == 0) ws[wid] = v;
    __syncthreads();
    if (threadIdx.x < 16) {
        int s = ws[threadIdx.x];
        #pragma unroll
        for (int d = 8; d > 0; d >>= 1) s += __shfl_down(s, d, 16);
        if (threadIdx.x == 0) bsum[blockIdx.x] = s;
    }
}

__global__ __launch_bounds__(512) void scanbase_kernel(const int* __restrict__ bsum,
                                                       int* __restrict__ base,
                                                       int* __restrict__ total, int nb) {
    __shared__ int ws[8];
    int t = threadIdx.x, lane = t & 63, wid = t >> 6;
    int v = (t < nb) ? bsum[t] : 0;
    int incl = v;
    #pragma unroll
    for (int d = 1; d < 64; d <<= 1) {
        int nv = __shfl_up(incl, d, 64);
        if (lane >= d) incl += nv;
    }
    if (lane == 63) ws[wid] = incl;
    __syncthreads();
    if (t < 8) {
        int s = ws[t], si = s;
        #pragma unroll
        for (int d = 1; d < 8; d <<= 1) {
            int nv = __shfl_up(si, d, 64);
            if (t >= d) si += nv;
        }
        ws[t] = si - s;   // exclusive wave base
    }
    __syncthreads();
    int excl = ws[wid] + incl - v;
    if (t < nb) base[t] = excl;
    if (t == 511) total[0] = ws[7] + incl;
}

__global__ __launch_bounds__(1024) void scanlocal_kernel(const int* __restrict__ counts,
                                                         const int* __restrict__ base,
                                                         int* __restrict__ offsets,
                                                         int* __restrict__ cursor, int n) {
    __shared__ int ws[16];
    __shared__ int wbase[16];
    int t = threadIdx.x;
    int i = blockIdx.x * 1024 + t;
    int v = (i < n) ? counts[i] : 0;
    int lane = t & 63, wid = t >> 6;
    int incl = v;
    #pragma unroll
    for (int d = 1; d < 64; d <<= 1) {
        int nv = __shfl_up(incl, d, 64);
        if (lane >= d) incl += nv;
    }
    if (lane == 63) ws[wid] = incl;
    __syncthreads();
    if (t < 16) {
        int s = ws[t], si = s;
        #pragma unroll
        for (int d = 1; d < 16; d <<= 1) {
            int nv = __shfl_up(si, d, 16);
            if (t >= d) si += nv;
        }
        wbase[t] = si - s;
    }
    __syncthreads();
    if (i < n) {
        int excl = base[blockIdx.x] + wbase[wid] + incl - v;
        offsets[i] = excl;
        cursor[i]  = excl;
    }
}

__global__ void fill_kernel(const int* __restrict__ src, const int* __restrict__ dst,
                            const int* __restrict__ et, int* __restrict__ cursor,
                            int* __restrict__ rows) {
    int e = blockIdx.x * 256 + threadIdx.x;
    if (e < NE) {
        int pos = atomicAdd(&cursor[dst[e]], 1);
        rows[pos] = et[e] * NN + src[e];   // row into rel[r][node][:]
    }
}

// ---------------- dtype prep ----------------
__global__ void cvt_bf16_kernel(const float* __restrict__ in, unsigned short* __restrict__ outp,
                                int n8) {
    int i = blockIdx.x * 256 + threadIdx.x;
    if (i >= n8) return;
    const float4* pp = (const float4*)in + (size_t)i * 2;
    float4 a = pp[0], b = pp[1];
    uint4 o;
    o.x = (unsigned)f2bf(a.x) | ((unsigned)f2bf(a.y) << 16);
    o.y = (unsigned)f2bf(a.z) | ((unsigned)f2bf(a.w) << 16);
    o.z = (unsigned)f2bf(b.x) | ((unsigned)f2bf(b.y) << 16);
    o.w = (unsigned)f2bf(b.z) | ((unsigned)f2bf(b.w) << 16);
    ((uint4*)outp)[i] = o;
}

// WT[(r*DOUTV+o)][k] bf16; r==8 -> Wself
template<int DOUTV>
__global__ void prepW_kernel(const float* __restrict__ W, const float* __restrict__ Wself,
                             unsigned short* __restrict__ WT) {
    int idx = blockIdx.x * 256 + threadIdx.x;
    if (idx >= 9 * DOUTV * 128) return;
    int k = idx & 127;
    int c = idx >> 7;
    int r = c / DOUTV;
    int o = c - r * DOUTV;
    float v = (r < 8) ? W[((size_t)r * 128 + k) * DOUTV + o]
                      : Wself[(size_t)k * DOUTV + o];
    WT[idx] = f2bf(v);
}

// ---------------- split MFMA GEMM (A in LDS, B from L2-resident global) ----------------
// C[m][n] = sum_k A[m][k] * WT[bn*NOUT+n][k], K=128. BM=128, 256 threads = 4 waves
// in 2x2 (wm 64, wn NOUT/2). LDS = Xs only (32 KB, XOR-swizzled) -> 5 blocks/CU.
// gridDim.y = 9: y<8 -> relation y (bf16 relout), y==8 -> self (fp32 selfout + bias).
template<int NOUT>
__global__ __launch_bounds__(256) void gemm_split(
        const unsigned short* __restrict__ A,     // [M][128] bf16
        const unsigned short* __restrict__ WT,    // [9*NOUT][128] bf16
        const float*  __restrict__ bias,          // [NOUT]
        unsigned short* __restrict__ relout,      // [NR][M][NOUT] bf16
        float*  __restrict__ selfout,             // [M][NOUT] fp32
        int M) {
    constexpr int NJ = NOUT / 32;     // n-tiles per wave
    __shared__ unsigned short Xs[128 * 128];      // 32 KB
    const int t  = threadIdx.x;
    const int mb = blockIdx.x;
    const int bn = blockIdx.y;        // 0..8

    #pragma unroll
    for (int i = 0; i < 8; i++) {
        int g = t + i * 256;              // 2048 16B chunks = 128 rows x 16
        int row = g >> 4, c = g & 15;
        int m = mb * 128 + row;
        uint4 v = make_uint4(0, 0, 0, 0);
        if (m < M) v = *(const uint4*)(A + ((size_t)m << 7) + c * 8);
        *(uint4*)((char*)Xs + row * 256 + ((c ^ (row & 15)) << 4)) = v;
    }
    __syncthreads();

    const int lane = t & 63;
    const int w    = t >> 6;
    const int wm   = (w & 1) * 64;
    const int wn   = (w >> 1) * (NOUT / 2);
    const int r15  = lane & 15;
    const int q    = lane >> 4;

    f32x4 acc[4][NJ] = {};
    #pragma unroll
    for (int ks = 0; ks < 4; ks++) {
        int c = (ks * 4 + q) ^ r15;
        bf16x8 af[4];
        #pragma unroll
        for (int i = 0; i < 4; i++)
            af[i] = *(const bf16x8*)((const char*)Xs + (wm + i * 16 + r15) * 256 + (c << 4));
        #pragma unroll
        for (int j = 0; j < NJ; j++) {
            bf16x8 bf = *(const bf16x8*)(WT +
                ((size_t)(bn * NOUT + wn + j * 16 + r15) << 7) + ks * 32 + q * 8);
            #pragma unroll
            for (int i = 0; i < 4; i++)
                acc[i][j] = __builtin_amdgcn_mfma_f32_16x16x32_bf16(af[i], bf, acc[i][j], 0, 0, 0);
        }
    }

    const int rowq = q * 4;
    if (bn < 8) {
        unsigned short* O = relout + (size_t)bn * M * NOUT;
        #pragma unroll
        for (int i = 0; i < 4; i++) {
            #pragma unroll
            for (int reg = 0; reg < 4; reg++) {
                int m = mb * 128 + wm + i * 16 + rowq + reg;
                if (m < M) {
                    #pragma unroll
                    for (int j = 0; j < NJ; j++)
                        O[(size_t)m * NOUT + wn + j * 16 + r15] = f2bf(acc[i][j][reg]);
                }
            }
        }
    } else {
        #pragma unroll
        for (int j = 0; j < NJ; j++) {
            float bv = bias[wn + j * 16 + r15];
            #pragma unroll
            for (int i = 0; i < 4; i++) {
                #pragma unroll
                for (int reg = 0; reg < 4; reg++) {
                    int m = mb * 128 + wm + i * 16 + rowq + reg;
                    if (m < M)
                        selfout[(size_t)m * NOUT + wn + j * 16 + r15] = acc[i][j][reg] + bv;
                }
            }
        }
    }
}

// ---------------- gathers: wave per node, 4-deep pipelined edge loop ----------------
// DIM=128: lane owns cols 2l,2l+1 (uint); acc init = hself; relu; bf16 out.
__global__ __launch_bounds__(256) void gather128(
        const int* __restrict__ offsets, const int* __restrict__ rows,
        const unsigned short* __restrict__ rel, const float* __restrict__ hself,
        unsigned short* __restrict__ hbf) {
    int wv = threadIdx.x >> 6, l = threadIdx.x & 63;
    int n = blockIdx.x * 4 + wv;
    int o0 = offsets[n], o1 = offsets[n + 1];
    float2 acc = *(const float2*)&hself[((size_t)n << 7) + 2 * l];
    const unsigned* R = (const unsigned*)rel;
    int j = o0;
    for (; j + 4 <= o1; j += 4) {
        int r0 = rows[j], r1 = rows[j + 1], r2 = rows[j + 2], r3 = rows[j + 3];
        unsigned p0 = R[((size_t)r0 << 6) + l];
        unsigned p1 = R[((size_t)r1 << 6) + l];
        unsigned p2 = R[((size_t)r2 << 6) + l];
        unsigned p3 = R[((size_t)r3 << 6) + l];
        acc.x += __uint_as_float(p0 << 16) + __uint_as_float(p1 << 16)
               + __uint_as_float(p2 << 16) + __uint_as_float(p3 << 16);
        acc.y += __uint_as_float(p0 & 0xffff0000u) + __uint_as_float(p1 & 0xffff0000u)
               + __uint_as_float(p2 & 0xffff0000u) + __uint_as_float(p3 & 0xffff0000u);
    }
    for (; j < o1; ++j) {
        unsigned p = R[((size_t)rows[j] << 6) + l];
        acc.x += __uint_as_float(p << 16);
        acc.y += __uint_as_float(p & 0xffff0000u);
    }
    acc.x = fmaxf(acc.x, 0.f);
    acc.y = fmaxf(acc.y, 0.f);
    ((unsigned*)hbf)[((size_t)n << 6) + l] = (unsigned)f2bf(acc.x) | ((unsigned)f2bf(acc.y) << 16);
}

// DIM=64: lane owns col l (ushort); acc init = out (self+bias already there); fp32 out.
__global__ __launch_bounds__(256) void gather64(
        const int* __restrict__ offsets, const int* __restrict__ rows,
        const unsigned short* __restrict__ rel, float* __restrict__ io) {
    int wv = threadIdx.x >> 6, l = threadIdx.x & 63;
    int n = blockIdx.x * 4 + wv;
    int o0 = offsets[n], o1 = offsets[n + 1];
    float acc = io[((size_t)n << 6) + l];
    int j = o0;
    for (; j + 4 <= o1; j += 4) {
        int r0 = rows[j], r1 = rows[j + 1], r2 = rows[j + 2], r3 = rows[j + 3];
        unsigned short v0 = rel[((size_t)r0 << 6) + l];
        unsigned short v1 = rel[((size_t)r1 << 6) + l];
        unsigned short v2 = rel[((size_t)r2 << 6) + l];
        unsigned short v3 = rel[((size_t)r3 << 6) + l];
        acc += bf2f(v0) + bf2f(v1) + bf2f(v2) + bf2f(v3);
    }
    for (; j < o1; ++j)
        acc += bf2f(rel[((size_t)rows[j] << 6) + l]);
    io[((size_t)n << 6) + l] = acc;
}

extern "C" void kernel_launch(void* const* d_in, const int* in_sizes, int n_in,
                              void* d_out, int out_size, void* d_ws, size_t ws_size,
                              hipStream_t stream) {
    const float* X   = (const float*)d_in[0];
    const int*   src = (const int*)d_in[1];
    const int*   dst = (const int*)d_in[2];
    const int*   et  = (const int*)d_in[3];
    const float* W1  = (const float*)d_in[4];
    const float* W1s = (const float*)d_in[5];
    const float* b1  = (const float*)d_in[6];
    const float* W2  = (const float*)d_in[7];
    const float* W2s = (const float*)d_in[8];
    const float* b2  = (const float*)d_in[9];
    float* out = (float*)d_out;

    // workspace carve (~145 MB)
    char* p = (char*)d_ws;
    unsigned short* rel = (unsigned short*)p; p += (size_t)NR * NN * 128 * 2;  // 102.4 MB (L2 reuses)
    float* hself = (float*)p;          p += (size_t)NN * 128 * 4;              // 25.6 MB
    unsigned short* Xbf = (unsigned short*)p; p += (size_t)NN * 128 * 2;       // 12.8 MB (reused as hbf)
    unsigned short* W1T = (unsigned short*)p; p += (size_t)9 * 128 * 128 * 2;  // 288 KB
    unsigned short* W2T = (unsigned short*)p; p += (size_t)9 * 64 * 128 * 2;   // 144 KB
    int* counts  = (int*)p; p += (size_t)NN * 4;
    int* offsets = (int*)p; p += (size_t)(NN + 4) * 4;
    int* cursor  = (int*)p; p += (size_t)NN * 4;
    int* rows    = (int*)p; p += (size_t)NE * 4;
    int* bsum    = (int*)p; p += 512 * 4;
    int* bbase   = (int*)p; p += 512 * 4;

    // dst-sorted CSR (shared by both layers)
    hipMemsetAsync(counts, 0, NN * sizeof(int), stream);
    hist_kernel<<<(NE + 255) / 256, 256, 0, stream>>>(dst, counts);
    blocksum_kernel<<<NB1, 1024, 0, stream>>>(counts, bsum, NN);
    scanbase_kernel<<<1, 512, 0, stream>>>(bsum, bbase, &offsets[NN], NB1);
    scanlocal_kernel<<<NB1, 1024, 0, stream>>>(counts, bbase, offsets, cursor, NN);
    fill_kernel<<<(NE + 255) / 256, 256, 0, stream>>>(src, dst, et, cursor, rows);

    // dtype prep
    cvt_bf16_kernel<<<(NN * 128 / 8 + 255) / 256, 256, 0, stream>>>(X, Xbf, NN * 128 / 8);
    prepW_kernel<128><<<(9 * 128 * 128 + 255) / 256, 256, 0, stream>>>(W1, W1s, W1T);
    prepW_kernel<64><<<(9 * 64 * 128 + 255) / 256, 256, 0, stream>>>(W2, W2s, W2T);

    const int mblocks = (NN + 127) / 128;   // 391
    const int gblocks = NN / 4;             // 12500

    // Layer 1: rel[r] = Xbf@W1[r] (bf16), hself = Xbf@W1s + b1 (fp32); h=relu(agg+hself)->bf16
    gemm_split<128><<<dim3(mblocks, 9), 256, 0, stream>>>(Xbf, W1T, b1, rel, hself, NN);
    gather128<<<gblocks, 256, 0, stream>>>(offsets, rows, rel, hself, Xbf);

    // Layer 2: rel2[r] = h@W2[r] (bf16, reuse rel), out = h@W2s + b2; out += agg2
    gemm_split<64><<<dim3(mblocks, 9), 256, 0, stream>>>(Xbf, W2T, b2, rel, out, NN);
    gather64<<<gblocks, 256, 0, stream>>>(offsets, rows, rel, out);
}